// Round 1
// baseline (3008.626 us; speedup 1.0000x reference)
//
#include <hip/hip_runtime.h>
#include <math.h>

#define BB 4
#define CC 64
#define NN 8192
#define OO 128
#define KK 20
#define NCH 4
#define CHSZ (NN / NCH)   // 2048
#define DD 128            // 2*CC

// ---------------------------------------------------------------------------
// prep: xt[b][n][c] = x[b][c][n] (transpose for row-contiguous gathers) and
//       xx[b][n] = sum_c x^2  (fp32, serial over c to track reference closely)
// ---------------------------------------------------------------------------
__global__ __launch_bounds__(128) void prep_kernel(const float* __restrict__ x,
                                                   float* __restrict__ xt,
                                                   float* __restrict__ xx) {
  __shared__ float tile[128][CC + 1];  // +1 pad: conflict-free read/write
  const int tid = threadIdx.x;
  const int b = blockIdx.y;
  const int n0 = blockIdx.x * 128;
  const float* xb = x + (size_t)b * CC * NN;
  float acc = 0.0f;
  #pragma unroll 8
  for (int c = 0; c < CC; ++c) {
    float v = xb[(size_t)c * NN + n0 + tid];   // coalesced over tid
    acc += v * v;
    tile[tid][c] = v;
  }
  xx[b * NN + n0 + tid] = acc;
  __syncthreads();
  float* xtb = xt + ((size_t)b * NN + n0) * CC;
  #pragma unroll 8
  for (int t = tid; t < 128 * CC; t += 128) {  // coalesced row writes
    xtb[t] = tile[t >> 6][t & 63];
  }
}

// ---------------------------------------------------------------------------
// knn: per (b, 64-query group, chunk) wave computes partial top-20 over a
// 2048-candidate chunk. Candidate tiles staged in LDS (broadcast reads).
// Register-resident top-20, all-static indexing (no scratch). Strict '>' so
// ties keep the earliest (lowest) index, matching jax.lax.top_k.
// ---------------------------------------------------------------------------
__global__ __launch_bounds__(64) void knn_kernel(const float* __restrict__ xt,
                                                 const float* __restrict__ xx,
                                                 float* __restrict__ pval,
                                                 int* __restrict__ pidx) {
  __shared__ float cand[64 * CC];   // 16 KB
  __shared__ float cxx[64];
  const int lane = threadIdx.x;
  const int b = blockIdx.z;
  const int ch = blockIdx.y;
  const int n = blockIdx.x * 64 + lane;
  const int m0 = ch * CHSZ;
  const float* xtb = xt + (size_t)b * NN * CC;

  float4 q[16];
  {
    const float4* qp = (const float4*)(xtb + (size_t)n * CC);
    #pragma unroll
    for (int i = 0; i < 16; ++i) q[i] = qp[i];
  }
  const float xxn = xx[b * NN + n];

  float tv[KK];
  int ti[KK];
  #pragma unroll
  for (int j = 0; j < KK; ++j) { tv[j] = -INFINITY; ti[j] = -1; }
  float minv = -INFINITY;

  for (int mt = 0; mt < CHSZ; mt += 64) {
    __syncthreads();
    {
      const float4* src = (const float4*)(xtb + (size_t)(m0 + mt) * CC);
      float4* dst = (float4*)cand;
      #pragma unroll
      for (int t = 0; t < 16; ++t) dst[lane + t * 64] = src[lane + t * 64];
      cxx[lane] = xx[b * NN + m0 + mt + lane];
    }
    __syncthreads();
    #pragma unroll 2
    for (int r = 0; r < 64; ++r) {
      const float4* cp = (const float4*)(cand + r * CC);  // broadcast reads
      float d0 = 0.f, d1 = 0.f, d2 = 0.f, d3 = 0.f;       // 4-way ILP
      #pragma unroll
      for (int i = 0; i < 4; ++i) {
        float4 c0 = cp[4 * i + 0], c1 = cp[4 * i + 1];
        float4 c2 = cp[4 * i + 2], c3 = cp[4 * i + 3];
        float4 q0 = q[4 * i + 0], q1 = q[4 * i + 1];
        float4 q2 = q[4 * i + 2], q3 = q[4 * i + 3];
        d0 += q0.x * c0.x + q0.y * c0.y + q0.z * c0.z + q0.w * c0.w;
        d1 += q1.x * c1.x + q1.y * c1.y + q1.z * c1.z + q1.w * c1.w;
        d2 += q2.x * c2.x + q2.y * c2.y + q2.z * c2.z + q2.w * c2.w;
        d3 += q3.x * c3.x + q3.y * c3.y + q3.z * c3.z + q3.w * c3.w;
      }
      float dot = (d0 + d1) + (d2 + d3);
      // match reference formula: pd = -xx[n] - (-2*dot) - xx[m]
      float pd = (-xxn - (-2.0f * dot)) - cxx[r];
      if (pd > minv) {
        const int mi = m0 + mt + r;
        bool done = false;
        #pragma unroll
        for (int j = 0; j < KK; ++j) {
          if (!done && tv[j] == minv) { tv[j] = pd; ti[j] = mi; done = true; }
        }
        minv = tv[0];
        #pragma unroll
        for (int j = 1; j < KK; ++j) minv = fminf(minv, tv[j]);
      }
    }
  }

  // sort desc by value, ties asc by index (fully unrolled bubble -> no scratch)
  #pragma unroll
  for (int a = 0; a < KK - 1; ++a) {
    #pragma unroll
    for (int j = 0; j < KK - 1 - a; ++j) {
      bool sw = (tv[j + 1] > tv[j]) || (tv[j + 1] == tv[j] && ti[j + 1] < ti[j]);
      float va = sw ? tv[j + 1] : tv[j];
      float vb = sw ? tv[j] : tv[j + 1];
      int ia = sw ? ti[j + 1] : ti[j];
      int ib = sw ? ti[j] : ti[j + 1];
      tv[j] = va; tv[j + 1] = vb; ti[j] = ia; ti[j + 1] = ib;
    }
  }
  size_t base = (((size_t)b * NN + n) * NCH + ch) * KK;
  #pragma unroll
  for (int j = 0; j < KK; ++j) {
    pval[base + j] = tv[j];
    pidx[base + j] = ti[j];
  }
}

// ---------------------------------------------------------------------------
// merge: per query, 4-way merge of sorted partial lists -> final top-20 idx.
// Cross-chunk ties resolved by lower index (chunks partition index ranges).
// ---------------------------------------------------------------------------
__global__ __launch_bounds__(256) void merge_kernel(const float* __restrict__ pval,
                                                    const int* __restrict__ pidx,
                                                    int* __restrict__ fidx) {
  const int q = blockIdx.x * 256 + threadIdx.x;  // q = b*NN + n
  const float* pv = pval + (size_t)q * NCH * KK;
  const int* pi = pidx + (size_t)q * NCH * KK;
  int p0 = 0, p1 = 0, p2 = 0, p3 = 0;
  float v0 = pv[0], v1 = pv[KK], v2 = pv[2 * KK], v3 = pv[3 * KK];
  int i0 = pi[0], i1 = pi[KK], i2 = pi[2 * KK], i3 = pi[3 * KK];
  int* fo = fidx + (size_t)q * KK;
  #pragma unroll
  for (int k = 0; k < KK; ++k) {
    float bv = v0; int bi = i0; int bc = 0;
    if (v1 > bv || (v1 == bv && i1 < bi)) { bv = v1; bi = i1; bc = 1; }
    if (v2 > bv || (v2 == bv && i2 < bi)) { bv = v2; bi = i2; bc = 2; }
    if (v3 > bv || (v3 == bv && i3 < bi)) { bv = v3; bi = i3; bc = 3; }
    fo[k] = bi;
    if (bc == 0)      { ++p0; v0 = (p0 < KK) ? pv[p0] : -INFINITY;          i0 = (p0 < KK) ? pi[p0] : 0x7fffffff; }
    else if (bc == 1) { ++p1; v1 = (p1 < KK) ? pv[KK + p1] : -INFINITY;     i1 = (p1 < KK) ? pi[KK + p1] : 0x7fffffff; }
    else if (bc == 2) { ++p2; v2 = (p2 < KK) ? pv[2 * KK + p2] : -INFINITY; i2 = (p2 < KK) ? pi[2 * KK + p2] : 0x7fffffff; }
    else              { ++p3; v3 = (p3 < KK) ? pv[3 * KK + p3] : -INFINITY; i3 = (p3 < KK) ? pi[3 * KK + p3] : 0x7fffffff; }
  }
}

// ---------------------------------------------------------------------------
// d1: per n compute h[k][d] = y_k . W1a_d + t_d  (t_d = z.(W1b_d - W1a_d)),
// softmax over k per d, then g[d] = sum_k feats[k][d]*gate[k][d].
// W1 staged transposed in LDS, XOR-swizzled (exactly 64 KB, conflict-free).
// Block = 256 threads = two independent 128-thread halves, each owns one n.
// ---------------------------------------------------------------------------
__global__ __launch_bounds__(256) void d1_kernel(const float* __restrict__ xt,
                                                 const float* __restrict__ W1,
                                                 const int* __restrict__ fidx,
                                                 float* __restrict__ gbuf) {
  __shared__ float w1t[DD * DD];  // [c][d] swizzled: addr = c*128 + (d ^ (c&31))
  const int tid = threadIdx.x;
  const int b = blockIdx.y;
  const int n0 = blockIdx.x * 32;
  for (int t = tid; t < DD * DD; t += 256) {
    int dd = t >> 7, c = t & 127;
    w1t[c * DD + (dd ^ (c & 31))] = W1[t];  // coalesced global read
  }
  __syncthreads();
  const int half = tid >> 7;
  const int d = tid & 127;
  const float* xtb = xt + (size_t)b * NN * CC;

  for (int i = 0; i < 16; ++i) {
    const int n = n0 + half + 2 * i;
    const int* kp = fidx + ((size_t)b * NN + n) * KK;
    int ki[KK];
    #pragma unroll
    for (int k = 0; k < KK; ++k) ki[k] = kp[k];

    float h[KK];
    #pragma unroll
    for (int k = 0; k < KK; ++k) h[k] = 0.0f;
    float td = 0.0f;
    const float4* zp = (const float4*)(xtb + (size_t)n * CC);
    for (int c4 = 0; c4 < 16; ++c4) {
      const int c = c4 * 4;
      float4 z4 = zp[c4];
      float wa0 = w1t[(c + 0) * DD + (d ^ ((c + 0) & 31))];
      float wa1 = w1t[(c + 1) * DD + (d ^ ((c + 1) & 31))];
      float wa2 = w1t[(c + 2) * DD + (d ^ ((c + 2) & 31))];
      float wa3 = w1t[(c + 3) * DD + (d ^ ((c + 3) & 31))];
      float wb0 = w1t[(c + 64) * DD + (d ^ ((c + 64) & 31))];
      float wb1 = w1t[(c + 65) * DD + (d ^ ((c + 65) & 31))];
      float wb2 = w1t[(c + 66) * DD + (d ^ ((c + 66) & 31))];
      float wb3 = w1t[(c + 67) * DD + (d ^ ((c + 67) & 31))];
      td += z4.x * (wb0 - wa0) + z4.y * (wb1 - wa1) + z4.z * (wb2 - wa2) + z4.w * (wb3 - wa3);
      #pragma unroll
      for (int k = 0; k < KK; ++k) {
        float4 y4 = *(const float4*)(xtb + (size_t)ki[k] * CC + c);  // wave-broadcast, L2-hot
        h[k] += y4.x * wa0 + y4.y * wa1 + y4.z * wa2 + y4.w * wa3;
      }
    }
    float m = h[0] + td;
    #pragma unroll
    for (int k = 0; k < KK; ++k) { h[k] += td; m = fmaxf(m, h[k]); }
    float e[KK];
    float s = 0.0f;
    #pragma unroll
    for (int k = 0; k < KK; ++k) { e[k] = expf(h[k] - m); s += e[k]; }
    const float inv = 1.0f / s;

    float g;
    if (d < 64) {  // wave-uniform branch
      const float zd = xtb[(size_t)n * CC + d];
      g = 0.0f;
      #pragma unroll
      for (int k = 0; k < KK; ++k) {
        const float yk = xtb[(size_t)ki[k] * CC + d];  // coalesced row read
        g += (yk - zd) * (e[k] * inv);
      }
    } else {
      const float zd = xtb[(size_t)n * CC + (d - 64)];
      float sg = 0.0f;
      #pragma unroll
      for (int k = 0; k < KK; ++k) sg += e[k] * inv;
      g = zd * sg;
    }
    gbuf[((size_t)b * NN + n) * DD + d] = g;
  }
}

// ---------------------------------------------------------------------------
// d2: out[b][o][n] = sum_c g[b][n][c] * W2[o][c].  W2 staged as swizzled
// float4 in LDS (exactly 64 KB). Thread -> (og, n), 16 o's per thread.
// ---------------------------------------------------------------------------
__global__ __launch_bounds__(256) void d2_kernel(const float* __restrict__ gbuf,
                                                 const float* __restrict__ W2,
                                                 float* __restrict__ out) {
  __shared__ float4 w2s[OO * 32];  // addr4 = o*32 + (c4 ^ (o&7))
  const int tid = threadIdx.x;
  const int b = blockIdx.y;
  const int n0 = blockIdx.x * 32;
  const float4* w2v = (const float4*)W2;
  for (int t = tid; t < OO * 32; t += 256) {
    int o = t >> 5, c4 = t & 31;
    w2s[o * 32 + (c4 ^ (o & 7))] = w2v[t];
  }
  __syncthreads();
  const int og = tid & 7;
  const int ni = tid >> 3;
  const int n = n0 + ni;
  const float4* gp = (const float4*)(gbuf + ((size_t)b * NN + n) * DD);
  float acc[16];
  #pragma unroll
  for (int j = 0; j < 16; ++j) acc[j] = 0.0f;
  for (int c4 = 0; c4 < 32; ++c4) {
    float4 g4 = gp[c4];
    #pragma unroll
    for (int j = 0; j < 16; ++j) {
      const int o = j * 8 + og;
      float4 w4 = w2s[o * 32 + (c4 ^ og)];
      acc[j] += g4.x * w4.x + g4.y * w4.y + g4.z * w4.z + g4.w * w4.w;
    }
  }
  float* outb = out + (size_t)b * OO * NN;
  #pragma unroll
  for (int j = 0; j < 16; ++j) {
    outb[(size_t)(j * 8 + og) * NN + n] = acc[j];
  }
}

// ---------------------------------------------------------------------------
// ws layout (bytes):
//   xt   @ 0          : 2,097,152 f32  =  8,388,608 B
//   xx   @ 8,388,608  :    32,768 f32  =    131,072 B
//   pval @ 8,519,680  : 2,621,440 f32  = 10,485,760 B   (dead after merge)
//   pidx @ 19,005,440 : 2,621,440 i32  = 10,485,760 B   (dead after merge)
//   fidx @ 29,491,200 :   655,360 i32  =  2,621,440 B
//   gbuf @ 8,519,680  : 4,194,304 f32  = 16,777,216 B   (reuses pval/pidx)
// total: 32,112,640 B (~30.6 MB)
// ---------------------------------------------------------------------------
extern "C" void kernel_launch(void* const* d_in, const int* in_sizes, int n_in,
                              void* d_out, int out_size, void* d_ws, size_t ws_size,
                              hipStream_t stream) {
  const float* x  = (const float*)d_in[0];
  const float* W1 = (const float*)d_in[1];
  const float* W2 = (const float*)d_in[2];
  float* out = (float*)d_out;
  char* ws = (char*)d_ws;
  float* xt   = (float*)(ws);
  float* xx   = (float*)(ws + 8388608);
  float* pval = (float*)(ws + 8519680);
  int*   pidx = (int*)  (ws + 19005440);
  int*   fidx = (int*)  (ws + 29491200);
  float* gbuf = (float*)(ws + 8519680);

  prep_kernel<<<dim3(NN / 128, BB), 128, 0, stream>>>(x, xt, xx);
  knn_kernel<<<dim3(NN / 64, NCH, BB), 64, 0, stream>>>(xt, xx, pval, pidx);
  merge_kernel<<<dim3(BB * NN / 256), 256, 0, stream>>>(pval, pidx, fidx);
  d1_kernel<<<dim3(NN / 32, BB), 256, 0, stream>>>(xt, W1, fidx, gbuf);
  d2_kernel<<<dim3(NN / 32, BB), 256, 0, stream>>>(gbuf, W2, out);
}